// Round 2
// baseline (1432.406 us; speedup 1.0000x reference)
//
#include <hip/hip_runtime.h>

// SparseInsGNBNIN: segmented GroupNorm over 2M rows x 64 ch, S=100 instances, G=32 groups.
// Three phases: (1) per-(seg,group) sum/sumsq via LDS atomics + global atomic flush,
// (2) finalize mean/inv table [S][G][2], (3) apply (x-mean)*inv*gamma+beta.

constexpr int S_INST = 100;   // num_instances (fixed by setup_inputs)
constexpr int NGRP   = 32;
constexpr int CCH    = 64;
constexpr float EPS  = 1e-5f;

// ---- K1: per-(segment, group) statistics -------------------------------
// One wave = 4 rows; 16 lanes per row, each lane loads float4 (channels 4c..4c+3),
// which spans groups 2c and 2c+1 (Cg=2). LDS layout padded to 33 per segment row
// so bank = (seg + 2c) % 32 spreads across banks.
__global__ __launch_bounds__(1024) void gn_stats(const float* __restrict__ x,
                                                 const int* __restrict__ idx,
                                                 int nrows,
                                                 float* __restrict__ gs1,
                                                 float* __restrict__ gs2,
                                                 float* __restrict__ gcnt) {
    __shared__ float ls1[S_INST * 33];
    __shared__ float ls2[S_INST * 33];
    __shared__ float lcnt[S_INST];
    for (int i = threadIdx.x; i < S_INST * 33; i += blockDim.x) { ls1[i] = 0.f; ls2[i] = 0.f; }
    for (int i = threadIdx.x; i < S_INST; i += blockDim.x) lcnt[i] = 0.f;
    __syncthreads();

    const int lane = threadIdx.x & 63;
    const int c    = lane & 15;   // float4 index within row (channels 4c..4c+3)
    const int rsub = lane >> 4;   // row within this wave's quad
    const int wave   = (blockIdx.x * blockDim.x + threadIdx.x) >> 6;
    const int nwaves = (gridDim.x * blockDim.x) >> 6;
    const int nq = (nrows + 3) >> 2;

    for (int q = wave; q < nq; q += nwaves) {
        const int row = q * 4 + rsub;
        if (row < nrows) {
            const int seg = idx[row];
            const float4 v = *reinterpret_cast<const float4*>(x + (size_t)row * CCH + c * 4);
            // channels 4c,4c+1 -> group 2c ; channels 4c+2,4c+3 -> group 2c+1
            atomicAdd(&ls1[seg * 33 + 2 * c],     v.x + v.y);
            atomicAdd(&ls2[seg * 33 + 2 * c],     v.x * v.x + v.y * v.y);
            atomicAdd(&ls1[seg * 33 + 2 * c + 1], v.z + v.w);
            atomicAdd(&ls2[seg * 33 + 2 * c + 1], v.z * v.z + v.w * v.w);
            if (c == 0) atomicAdd(&lcnt[seg], 1.0f);  // row count per segment
        }
    }
    __syncthreads();

    // Flush block-local partials to the global (L2-resident, 26 KB) accumulators.
    for (int i = threadIdx.x; i < S_INST * NGRP; i += blockDim.x) {
        const int s = i >> 5, g = i & 31;
        const float a = ls1[s * 33 + g];
        const float b = ls2[s * 33 + g];
        if (a != 0.f || b != 0.f) {
            atomicAdd(&gs1[i], a);
            atomicAdd(&gs2[i], b);
        }
    }
    for (int i = threadIdx.x; i < S_INST; i += blockDim.x) {
        const float cv = lcnt[i];
        if (cv != 0.f) atomicAdd(&gcnt[i], cv);
    }
}

// ---- K2: finalize mean/inv --------------------------------------------
// mi layout: [s][g][{mean, inv}] interleaved -> float4 at (s*64 + 4c) covers
// groups 2c and 2c+1, exactly what one K3 lane needs.
__global__ void gn_finalize(const float* __restrict__ gs1,
                            const float* __restrict__ gs2,
                            const float* __restrict__ gcnt,
                            float* __restrict__ mi) {
    const int i = blockIdx.x * blockDim.x + threadIdx.x;
    if (i >= S_INST * NGRP) return;
    const int s = i >> 5;
    const float denom = fmaxf(gcnt[s] * 2.0f, 1.0f);   // cnt = rows * Cg, guarded
    const float mean = gs1[i] / denom;
    const float var  = gs2[i] / denom - mean * mean;   // biased, as reference
    const float inv  = rsqrtf(var + EPS);
    mi[i * 2]     = mean;
    mi[i * 2 + 1] = inv;
}

// ---- K3: apply ---------------------------------------------------------
__global__ __launch_bounds__(256) void gn_apply(const float* __restrict__ x,
                                                const int* __restrict__ idx,
                                                const float* __restrict__ mi,
                                                const float* __restrict__ gamma,
                                                const float* __restrict__ beta,
                                                int nrows,
                                                float* __restrict__ out) {
    const int lane = threadIdx.x & 63;
    const int c    = lane & 15;
    const int rsub = lane >> 4;
    // gamma/beta for this lane's 4 channels are loop-invariant -> registers.
    const float4 gm = *reinterpret_cast<const float4*>(gamma + c * 4);
    const float4 bt = *reinterpret_cast<const float4*>(beta  + c * 4);
    const int wave   = (blockIdx.x * blockDim.x + threadIdx.x) >> 6;
    const int nwaves = (gridDim.x * blockDim.x) >> 6;
    const int nq = (nrows + 3) >> 2;

    for (int q = wave; q < nq; q += nwaves) {
        const int row = q * 4 + rsub;
        if (row < nrows) {
            const int seg = idx[row];
            const float4 v = *reinterpret_cast<const float4*>(x  + (size_t)row * CCH + c * 4);
            const float4 m = *reinterpret_cast<const float4*>(mi + seg * 64 + c * 4);
            float4 o;
            o.x = (v.x - m.x) * m.y * gm.x + bt.x;
            o.y = (v.y - m.x) * m.y * gm.y + bt.y;
            o.z = (v.z - m.z) * m.w * gm.z + bt.z;
            o.w = (v.w - m.z) * m.w * gm.w + bt.w;
            *reinterpret_cast<float4*>(out + (size_t)row * CCH + c * 4) = o;
        }
    }
}

extern "C" void kernel_launch(void* const* d_in, const int* in_sizes, int n_in,
                              void* d_out, int out_size, void* d_ws, size_t ws_size,
                              hipStream_t stream) {
    const float* x     = (const float*)d_in[0];
    const float* gamma = (const float*)d_in[1];
    const float* beta  = (const float*)d_in[2];
    const int*   idx   = (const int*)d_in[3];
    const int nrows = in_sizes[0] / CCH;

    float* ws   = (float*)d_ws;
    float* gs1  = ws;           // S*G = 3200
    float* gs2  = ws + 3200;    // 3200
    float* gcnt = ws + 6400;    // 100
    float* mi   = ws + 6500;    // S*C = 6400 (mean/inv interleaved per group)

    // ws is poisoned to 0xAA before every launch -> zero the accumulators.
    hipMemsetAsync(d_ws, 0, 6500 * sizeof(float), stream);

    gn_stats<<<512, 1024, 0, stream>>>(x, idx, nrows, gs1, gs2, gcnt);
    gn_finalize<<<(S_INST * NGRP + 255) / 256, 256, 0, stream>>>(gs1, gs2, gcnt, mi);
    gn_apply<<<2048, 256, 0, stream>>>(x, idx, mi, gamma, beta, nrows, (float*)d_out);
}